// Round 11
// baseline (129.578 us; speedup 1.0000x reference)
//
#include <hip/hip_runtime.h>

// B=16, T=512, D=384, target_len=4096. x: f32, durations: int32 (sniffed
// f32/i64/i32/i16), out: f32.
// R10 post-mortem: expand ~31us (3.8 TB/s) — per-thread dependent chain
// (idx load -> x load -> store) x2 sequential gave too little MLP. This
// version: 16 rows/block, phase-batched (4 idx loads || 4 gathers || 4 NT
// stores) -> 4 chains in flight per thread, 24 KB contiguous write/block.
#define B_   16
#define T_   512
#define TLEN 4096
#define XC   96    // 16B f32 chunks per row (384*4/16)
#define RPB  16    // rows per expand block (4 passes x 4 rows)
#define SENT 0xFFFFu

typedef float f4v __attribute__((ext_vector_type(4)));

__device__ __forceinline__ int sniff_dur(const unsigned int* __restrict__ durw,
                                         int e) {
    // dtype sniff on first 32 words (deterministic, uniform; values 0..15)
    int f32ok = 1, i64ok = 1, i32ok = 1, i16ok = 1;
    #pragma unroll
    for (int k = 0; k < 32; ++k) {
        unsigned w = durw[k];
        f32ok &= (int)((w == 0u) | ((w >= 0x3F800000u) & (w <= 0x41700000u)));
        i64ok &= (int)((k & 1) ? (w == 0u) : (w <= 15u));
        i32ok &= (int)(w <= 15u);
        i16ok &= (int)(((w & 0xFFFFu) <= 15u) & ((w >> 16) <= 15u));
    }
    int v;
    if (f32ok)      v = (int)__uint_as_float(durw[e]);
    else if (i64ok) v = (int)durw[e * 2];
    else if (i32ok) v = (int)durw[e];
    else if (i16ok) v = (int)((durw[e >> 1] >> (16 * (e & 1))) & 0xFFFFu);
    else            v = (int)durw[e];
    return v;
}

// Kernel 1: per-batch scan + scatter-inverse -> idx map (u16, 0xFFFF = pad).
__global__ __launch_bounds__(T_) void lr_build_idx(const unsigned int* __restrict__ durw,
                                                   unsigned short* __restrict__ idx) {
    __shared__ int s[T_];
    const int b = blockIdx.x;
    const int t = threadIdx.x;

    int v = sniff_dur(durw, b * T_ + t);
    s[t] = v < 1 ? 1 : v;
    __syncthreads();
    for (int off = 1; off < T_; off <<= 1) {
        int add = (t >= off) ? s[t - off] : 0;
        __syncthreads();
        s[t] += add;
        __syncthreads();
    }
    const int cum  = s[t];
    const int prev = t ? s[t - 1] : 0;   // safe: loop ended with a barrier

    unsigned short* row = idx + b * TLEN;
    for (int i = t; i < TLEN; i += T_) row[i] = (unsigned short)SENT;
    __syncthreads();

    const int end = cum < TLEN ? cum : TLEN;   // token t covers [prev, end)
    for (int j = prev; j < end; ++j) row[j] = (unsigned short)t;
}

// Kernel 2: search-free gather-stream, phase-batched for MLP.
// 4096 blocks x 384 threads; 96 lanes per row, 4 rows per pass, 4 passes.
__global__ __launch_bounds__(384) void lr_expand_idx(const f4v* __restrict__ x,
                                                     const unsigned short* __restrict__ idx,
                                                     f4v* __restrict__ out) {
    const int tid = threadIdx.x;
    const int sub = tid / XC;              // 0..3
    const int col = tid - sub * XC;        // 0..95
    const int row0 = blockIdx.x * RPB + sub;
    const int b = (blockIdx.x * RPB) >> 12;    // 4096 rows/batch, no straddle

    // Phase 1: all idx loads (independent, broadcast across the row's lanes)
    unsigned iv[4];
    #pragma unroll
    for (int p = 0; p < 4; ++p) iv[p] = idx[row0 + p * 4];

    // Phase 2: all gathers (L2/L3-hot x rows) — 4 chains in flight
    f4v v[4];
    #pragma unroll
    for (int p = 0; p < 4; ++p) {
        v[p] = (f4v){0.f, 0.f, 0.f, 0.f};
        if (iv[p] != SENT) v[p] = x[(b * T_ + (int)iv[p]) * XC + col];
    }

    // Phase 3: all stores — write-once 100MB stream, nontemporal
    #pragma unroll
    for (int p = 0; p < 4; ++p)
        __builtin_nontemporal_store(v[p], &out[(size_t)(row0 + p * 4) * XC + col]);
}

// ---- Fallback (ws too small for idx map): cum + binary search ----
__global__ __launch_bounds__(T_) void lr_scan(const unsigned int* __restrict__ durw,
                                              int* __restrict__ cum) {
    __shared__ int s[T_];
    const int b = blockIdx.x;
    const int t = threadIdx.x;
    int v = sniff_dur(durw, b * T_ + t);
    s[t] = v < 1 ? 1 : v;
    __syncthreads();
    for (int off = 1; off < T_; off <<= 1) {
        int add = (t >= off) ? s[t - off] : 0;
        __syncthreads();
        s[t] += add;
        __syncthreads();
    }
    cum[b * T_ + t] = s[t];
}

__global__ __launch_bounds__(384) void lr_expand(const f4v* __restrict__ x,
                                                 const int* __restrict__ cum,
                                                 f4v* __restrict__ out) {
    __shared__ int sc[T_];
    const int tid  = threadIdx.x;
    const int row0 = blockIdx.x * 32;
    const int b    = row0 >> 12;
    for (int i = tid; i < T_; i += 384) sc[i] = cum[b * T_ + i];
    __syncthreads();
    const int total = sc[T_ - 1];
    const int sub = tid / XC;
    const int col = tid - sub * XC;
    #pragma unroll
    for (int p = 0; p < 8; ++p) {
        const int row = row0 + p * 4 + sub;
        const int t   = row & (TLEN - 1);
        f4v val = (f4v){0.f, 0.f, 0.f, 0.f};
        if (t < total) {
            int lo = 0, hi = T_;
            #pragma unroll
            for (int i = 0; i < 10; ++i) {   // 513 outcomes -> 10 iters
                int mid = (lo + hi) >> 1;
                if (sc[mid] > t) hi = mid; else lo = mid + 1;
            }
            const int idx2 = lo > (T_ - 1) ? (T_ - 1) : lo;
            val = x[(b * T_ + idx2) * XC + col];
        }
        __builtin_nontemporal_store(val, &out[(size_t)row * XC + col]);
    }
}

extern "C" void kernel_launch(void* const* d_in, const int* in_sizes, int n_in,
                              void* d_out, int out_size, void* d_ws, size_t ws_size,
                              hipStream_t stream) {
    // d_in[0]=x, d_in[1]=durations, d_in[2]=target_len (shapes fixed).
    const f4v* x = (const f4v*)d_in[0];
    const unsigned int* durw = (const unsigned int*)d_in[1];

    if (ws_size >= (size_t)(B_ * TLEN * 2)) {         // 128 KB idx map
        unsigned short* idx = (unsigned short*)d_ws;
        lr_build_idx<<<B_, T_, 0, stream>>>(durw, idx);
        lr_expand_idx<<<(B_ * TLEN) / RPB, 384, 0, stream>>>(x, idx, (f4v*)d_out);
    } else {                                          // 32 KB cum fallback
        int* cum = (int*)d_ws;
        lr_scan<<<B_, T_, 0, stream>>>(durw, cum);
        lr_expand<<<(B_ * TLEN) / 32, 384, 0, stream>>>(x, cum, (f4v*)d_out);
    }
}

// Round 12
// 125.439 us; speedup vs baseline: 1.0330x; 1.0330x over previous
//
#include <hip/hip_runtime.h>

// B=16, T=512, D=384, target_len=4096. x: f32, durations: int32 (sniffed
// f32/i64/i32/i16), out: f32.
// R11 post-mortem: phase-batching neutral -> MLP not the limiter. Expand at
// ~31us (3.7 TB/s) vs harness fill at 6.4 TB/s. Single untested variable vs
// the fill kernel: nontemporal stores (used in EVERY round so far). This
// round: plain stores (L2 writeback path), all else identical to R11.
#define B_   16
#define T_   512
#define TLEN 4096
#define XC   96    // 16B f32 chunks per row (384*4/16)
#define RPB  16    // rows per expand block (4 passes x 4 rows)
#define SENT 0xFFFFu

typedef float f4v __attribute__((ext_vector_type(4)));

__device__ __forceinline__ int sniff_dur(const unsigned int* __restrict__ durw,
                                         int e) {
    // dtype sniff on first 32 words (deterministic, uniform; values 0..15)
    int f32ok = 1, i64ok = 1, i32ok = 1, i16ok = 1;
    #pragma unroll
    for (int k = 0; k < 32; ++k) {
        unsigned w = durw[k];
        f32ok &= (int)((w == 0u) | ((w >= 0x3F800000u) & (w <= 0x41700000u)));
        i64ok &= (int)((k & 1) ? (w == 0u) : (w <= 15u));
        i32ok &= (int)(w <= 15u);
        i16ok &= (int)(((w & 0xFFFFu) <= 15u) & ((w >> 16) <= 15u));
    }
    int v;
    if (f32ok)      v = (int)__uint_as_float(durw[e]);
    else if (i64ok) v = (int)durw[e * 2];
    else if (i32ok) v = (int)durw[e];
    else if (i16ok) v = (int)((durw[e >> 1] >> (16 * (e & 1))) & 0xFFFFu);
    else            v = (int)durw[e];
    return v;
}

// Kernel 1: per-batch scan + scatter-inverse -> idx map (u16, 0xFFFF = pad).
__global__ __launch_bounds__(T_) void lr_build_idx(const unsigned int* __restrict__ durw,
                                                   unsigned short* __restrict__ idx) {
    __shared__ int s[T_];
    const int b = blockIdx.x;
    const int t = threadIdx.x;

    int v = sniff_dur(durw, b * T_ + t);
    s[t] = v < 1 ? 1 : v;
    __syncthreads();
    for (int off = 1; off < T_; off <<= 1) {
        int add = (t >= off) ? s[t - off] : 0;
        __syncthreads();
        s[t] += add;
        __syncthreads();
    }
    const int cum  = s[t];
    const int prev = t ? s[t - 1] : 0;   // safe: loop ended with a barrier

    unsigned short* row = idx + b * TLEN;
    for (int i = t; i < TLEN; i += T_) row[i] = (unsigned short)SENT;
    __syncthreads();

    const int end = cum < TLEN ? cum : TLEN;   // token t covers [prev, end)
    for (int j = prev; j < end; ++j) row[j] = (unsigned short)t;
}

// Kernel 2: search-free gather-stream, phase-batched.
// 4096 blocks x 384 threads; 96 lanes per row, 4 rows per pass, 4 passes.
__global__ __launch_bounds__(384) void lr_expand_idx(const f4v* __restrict__ x,
                                                     const unsigned short* __restrict__ idx,
                                                     f4v* __restrict__ out) {
    const int tid = threadIdx.x;
    const int sub = tid / XC;              // 0..3
    const int col = tid - sub * XC;        // 0..95
    const int row0 = blockIdx.x * RPB + sub;
    const int b = (blockIdx.x * RPB) >> 12;    // 4096 rows/batch, no straddle

    // Phase 1: all idx loads (independent, broadcast across the row's lanes)
    unsigned iv[4];
    #pragma unroll
    for (int p = 0; p < 4; ++p) iv[p] = idx[row0 + p * 4];

    // Phase 2: all gathers (L3-hot x rows) — 4 chains in flight
    f4v v[4];
    #pragma unroll
    for (int p = 0; p < 4; ++p) {
        v[p] = (f4v){0.f, 0.f, 0.f, 0.f};
        if (iv[p] != SENT) v[p] = x[(b * T_ + (int)iv[p]) * XC + col];
    }

    // Phase 3: all stores — PLAIN stores this round (L2 writeback path,
    // same as the 6.4 TB/s harness fill kernel). NT was used in every
    // prior round and is the untested variable.
    #pragma unroll
    for (int p = 0; p < 4; ++p)
        out[(size_t)(row0 + p * 4) * XC + col] = v[p];
}

// ---- Fallback (ws too small for idx map): cum + binary search ----
__global__ __launch_bounds__(T_) void lr_scan(const unsigned int* __restrict__ durw,
                                              int* __restrict__ cum) {
    __shared__ int s[T_];
    const int b = blockIdx.x;
    const int t = threadIdx.x;
    int v = sniff_dur(durw, b * T_ + t);
    s[t] = v < 1 ? 1 : v;
    __syncthreads();
    for (int off = 1; off < T_; off <<= 1) {
        int add = (t >= off) ? s[t - off] : 0;
        __syncthreads();
        s[t] += add;
        __syncthreads();
    }
    cum[b * T_ + t] = s[t];
}

__global__ __launch_bounds__(384) void lr_expand(const f4v* __restrict__ x,
                                                 const int* __restrict__ cum,
                                                 f4v* __restrict__ out) {
    __shared__ int sc[T_];
    const int tid  = threadIdx.x;
    const int row0 = blockIdx.x * 32;
    const int b    = row0 >> 12;
    for (int i = tid; i < T_; i += 384) sc[i] = cum[b * T_ + i];
    __syncthreads();
    const int total = sc[T_ - 1];
    const int sub = tid / XC;
    const int col = tid - sub * XC;
    #pragma unroll
    for (int p = 0; p < 8; ++p) {
        const int row = row0 + p * 4 + sub;
        const int t   = row & (TLEN - 1);
        f4v val = (f4v){0.f, 0.f, 0.f, 0.f};
        if (t < total) {
            int lo = 0, hi = T_;
            #pragma unroll
            for (int i = 0; i < 10; ++i) {   // 513 outcomes -> 10 iters
                int mid = (lo + hi) >> 1;
                if (sc[mid] > t) hi = mid; else lo = mid + 1;
            }
            const int idx2 = lo > (T_ - 1) ? (T_ - 1) : lo;
            val = x[(b * T_ + idx2) * XC + col];
        }
        out[(size_t)row * XC + col] = val;
    }
}

extern "C" void kernel_launch(void* const* d_in, const int* in_sizes, int n_in,
                              void* d_out, int out_size, void* d_ws, size_t ws_size,
                              hipStream_t stream) {
    // d_in[0]=x, d_in[1]=durations, d_in[2]=target_len (shapes fixed).
    const f4v* x = (const f4v*)d_in[0];
    const unsigned int* durw = (const unsigned int*)d_in[1];

    if (ws_size >= (size_t)(B_ * TLEN * 2)) {         // 128 KB idx map
        unsigned short* idx = (unsigned short*)d_ws;
        lr_build_idx<<<B_, T_, 0, stream>>>(durw, idx);
        lr_expand_idx<<<(B_ * TLEN) / RPB, 384, 0, stream>>>(x, idx, (f4v*)d_out);
    } else {                                          // 32 KB cum fallback
        int* cum = (int*)d_ws;
        lr_scan<<<B_, T_, 0, stream>>>(durw, cum);
        lr_expand<<<(B_ * TLEN) / 32, 384, 0, stream>>>(x, cum, (f4v*)d_out);
    }
}